// Round 4
// baseline (444.996 us; speedup 1.0000x reference)
//
#include <hip/hip_runtime.h>
#include <math.h>

// GAT layer, round 4: Adj -> bitmask pre-pass (streaming), register-only MFMA
// attention (no LDS, no Adj in the hot kernel).
// N=8192, IN=512, D=64, ALPHA=0.2
//
// ws layout (float-slot units):
//   h     : [8192][64] f32                524288
//   s1    : [8192] f32                      8192
//   s2    : [8192] f32                      8192
//   hFrag : [256 jblk][4 dt][64 lane] bf16x8 -> 262144 float slots
//   mask  : [8192 row][256 chunk] u32   -> 2097152 u32 = 2097152 float slots (8 MB)
//   numP  : [1024][64][64] f32            4194304
//   denP  : [1024][64] f32                  65536

#define NN 8192
#define KIN 512
#define DD 64
#define ALPHA 0.2f

using floatx4 = __attribute__((ext_vector_type(4))) float;
using bf16x8  = __attribute__((ext_vector_type(8))) __bf16;

// ---------------- Kernel 1: h = X @ W (fp32, 256 blocks x 32 rows) ----------------
__global__ __launch_bounds__(256) void k_gemm_h(const float* __restrict__ X,
                                                const float* __restrict__ W,
                                                float* __restrict__ h) {
    __shared__ __align__(16) float XT[32 * 36];  // [k][row], stride 36
    __shared__ __align__(16) float WL[32 * 64];  // [k][d]
    const int t = threadIdx.x;
    const int i0 = blockIdx.x * 32;
    const int rb = t >> 5;   // rows rb*4..+3
    const int db = t & 31;   // dims db*2..+1
    float acc[4][2] = {};

    for (int k0 = 0; k0 < KIN; k0 += 32) {
        {
            const int row = t >> 3, kq = t & 7;
            const float4 x4 = *(const float4*)(X + (size_t)(i0 + row) * KIN + k0 + kq * 4);
            XT[(kq * 4 + 0) * 36 + row] = x4.x;
            XT[(kq * 4 + 1) * 36 + row] = x4.y;
            XT[(kq * 4 + 2) * 36 + row] = x4.z;
            XT[(kq * 4 + 3) * 36 + row] = x4.w;
#pragma unroll
            for (int p = 0; p < 2; ++p) {
                const int q = p * 256 + t;  // 0..511
                const int kk = q >> 4, dq = q & 15;
                *(float4*)(WL + kk * 64 + dq * 4) =
                    *(const float4*)(W + (size_t)(k0 + kk) * DD + dq * 4);
            }
        }
        __syncthreads();
#pragma unroll
        for (int k = 0; k < 32; ++k) {
            const float4 xa = *(const float4*)(XT + k * 36 + rb * 4);
            const float2 wb = *(const float2*)(WL + k * 64 + db * 2);
            const float xv[4] = {xa.x, xa.y, xa.z, xa.w};
#pragma unroll
            for (int i = 0; i < 4; ++i) {
                acc[i][0] += xv[i] * wb.x;
                acc[i][1] += xv[i] * wb.y;
            }
        }
        __syncthreads();
    }
#pragma unroll
    for (int i = 0; i < 4; ++i) {
        float2 o = {acc[i][0], acc[i][1]};
        *(float2*)(h + (size_t)(i0 + rb * 4 + i) * DD + db * 2) = o;
    }
}

// ---------------- Kernel 2: s1/s2 = h @ a1, h @ a2 ----------------
__global__ __launch_bounds__(256) void k_s12(const float* __restrict__ h,
                                             const float* __restrict__ a,
                                             float* __restrict__ s1,
                                             float* __restrict__ s2) {
    const int lane = threadIdx.x & 63;
    const int w = threadIdx.x >> 6;
    const int r = blockIdx.x * 4 + w;
    const float v = h[(size_t)r * DD + lane];
    float p1 = v * a[lane];
    float p2 = v * a[64 + lane];
#pragma unroll
    for (int off = 32; off; off >>= 1) {
        p1 += __shfl_xor(p1, off, 64);
        p2 += __shfl_xor(p2, off, 64);
    }
    if (lane == 0) {
        s1[r] = p1;
        s2[r] = p2;
    }
}

// ---------------- Kernel 3: pack h into MFMA B-fragments (bf16) ----------------
// hFrag[jblk][dt][lane][jj] = bf16( h[jblk*32 + (lane>>4)*8 + jj][dt*16 + (lane&15)] )
__global__ __launch_bounds__(256) void k_hfrag(const float* __restrict__ h,
                                               __bf16* __restrict__ hFrag) {
    const int f = blockIdx.x * 256 + threadIdx.x;  // 0..65535
    const int lane = f & 63, dt = (f >> 6) & 3, jblk = f >> 8;
    const int n = lane & 15, q = lane >> 4;
    bf16x8 v;
#pragma unroll
    for (int jj = 0; jj < 8; ++jj)
        v[jj] = (__bf16)h[(size_t)(jblk * 32 + q * 8 + jj) * DD + dt * 16 + n];
    *(bf16x8*)(hFrag + (size_t)f * 8) = v;
}

// ---------------- Kernel 4: Adj -> bitmask (pure streaming, fill-like) ----------------
// mask u32 chunk c, bit b  <->  Adj[flat c*32 + b]  (row r chunk = mask[r*256 + ...])
// Wave-iter: 512 consecutive ints, 8 coalesced 256B dword loads, 8 ballots, 64B store.
__global__ __launch_bounds__(256) void k_pack(const int* __restrict__ Adj,
                                              unsigned int* __restrict__ mask) {
    const int lane = threadIdx.x & 63;
    const int wid = (blockIdx.x * 256 + threadIdx.x) >> 6;
    const int nw = (gridDim.x * 256) >> 6;
    for (int it = wid; it < (NN * NN / 512); it += nw) {
        const size_t base = (size_t)it * 512;
        unsigned long long m[8];
#pragma unroll
        for (int p = 0; p < 8; ++p) {
            const int v = Adj[base + (size_t)p * 64 + lane];
            m[p] = __ballot(v != 0);
        }
        if (lane == 0) {
            unsigned long long* o = (unsigned long long*)mask + (size_t)it * 8;
#pragma unroll
            for (int p = 0; p < 8; ++p) o[p] = m[p];
        }
    }
}

// ---------------- Kernel 5: fused masked-softmax numerator via MFMA ----------------
// grid = 128 i-tiles x 8 j-chunks = 1024 blocks, 256 threads (4 waves), NO LDS.
// Lane (n = lane&15, q = lane>>4) of wave wv owns E-row i0+wv*16+n; per K-step ks
// it computes A-fragment elements for j = jc*1024 + ks*32 + q*8 + jj directly in
// registers from the preloaded bitmask (32 VGPRs) + broadcast s2.
__global__ __launch_bounds__(256, 4) void k_attn4(const bf16x8* __restrict__ hFrag,
                                                  const unsigned int* __restrict__ mask,
                                                  const float* __restrict__ s1,
                                                  const float* __restrict__ s2,
                                                  float* __restrict__ numP,
                                                  float* __restrict__ denP) {
    const int t = threadIdx.x;
    const int wv = t >> 6;
    const int lane = t & 63;
    const int n = lane & 15, q = lane >> 4;
    const int it = blockIdx.x >> 3, jc = blockIdx.x & 7;
    const int i0 = it * 64;
    const int row = i0 + wv * 16 + n;
    const float s1v = s1[row];

    // preload this row's 32 mask chunks covering j = [jc*1024, jc*1024+1024)
    unsigned int mr[32];
    {
        const uint4* mp = (const uint4*)(mask + (size_t)row * 256 + jc * 32);
#pragma unroll
        for (int p = 0; p < 8; ++p) {
            const uint4 v = mp[p];
            mr[p * 4 + 0] = v.x;
            mr[p * 4 + 1] = v.y;
            mr[p * 4 + 2] = v.z;
            mr[p * 4 + 3] = v.w;
        }
    }

    bf16x8 ones;
#pragma unroll
    for (int u = 0; u < 8; ++u) ones[u] = (__bf16)1.0f;

    floatx4 acc[5] = {};  // 4 d-tiles + denominator (B = ones)
    const int jbase = jc * 1024;

#pragma unroll
    for (int ks = 0; ks < 32; ++ks) {
        const int j0 = jbase + ks * 32 + q * 8;
        const float4 z0 = *(const float4*)(s2 + j0);
        const float4 z1 = *(const float4*)(s2 + j0 + 4);
        const unsigned int bits = (mr[ks] >> (q * 8)) & 0xffu;
        const float zz[8] = {z0.x, z0.y, z0.z, z0.w, z1.x, z1.y, z1.z, z1.w};
        bf16x8 af;
#pragma unroll
        for (int u = 0; u < 8; ++u) {
            const float s = s1v + zz[u];
            const float l = fmaxf(s, ALPHA * s);  // leaky-relu (alpha<1)
            const float e = (bits & (1u << u)) ? __expf(l) : 0.f;
            af[u] = (__bf16)e;
        }
        const bf16x8* hf = hFrag + ((size_t)(jc * 32 + ks) * 4) * 64 + lane;
#pragma unroll
        for (int dt = 0; dt < 4; ++dt)
            acc[dt] = __builtin_amdgcn_mfma_f32_16x16x32_bf16(af, hf[dt * 64], acc[dt], 0, 0, 0);
        acc[4] = __builtin_amdgcn_mfma_f32_16x16x32_bf16(af, ones, acc[4], 0, 0, 0);
    }

    // numerator partials: D row m = q*4+reg, col = dt*16+n
    const size_t base = (size_t)blockIdx.x * 4096;
#pragma unroll
    for (int dt = 0; dt < 4; ++dt)
#pragma unroll
        for (int r = 0; r < 4; ++r)
            numP[base + (size_t)(wv * 16 + q * 4 + r) * 64 + dt * 16 + n] = acc[dt][r];

    // denominator: every col of acc[4] holds the row-sum; lane n==0 writes its 4 rows
    if (n == 0) {
#pragma unroll
        for (int r = 0; r < 4; ++r)
            denP[(size_t)blockIdx.x * 64 + wv * 16 + q * 4 + r] = acc[4][r];
    }
}

// ---------------- Kernel 6: reduce partials + normalize ----------------
__global__ __launch_bounds__(256) void k_final(const float* __restrict__ numP,
                                               const float* __restrict__ denP,
                                               float* __restrict__ out) {
    const int idx = blockIdx.x * 256 + threadIdx.x;  // 0..524287
    const int i = idx >> 6, d = idx & 63;
    const int it = i >> 6, r = i & 63;
    float num = 0.f, den = 0.f;
#pragma unroll
    for (int c = 0; c < 8; ++c) {
        const size_t bx = (size_t)(it * 8 + c);
        num += numP[bx * 4096 + (size_t)r * 64 + d];
        den += denP[bx * 64 + r];
    }
    out[idx] = num / den;
}

extern "C" void kernel_launch(void* const* d_in, const int* in_sizes, int n_in,
                              void* d_out, int out_size, void* d_ws, size_t ws_size,
                              hipStream_t stream) {
    const float* X = (const float*)d_in[0];
    const int* Adj = (const int*)d_in[1];
    const float* W = (const float*)d_in[2];
    const float* a = (const float*)d_in[3];
    float* out = (float*)d_out;

    float* ws = (float*)d_ws;
    float* h = ws;                             // 524288
    float* s1 = h + 524288;                    // 8192
    float* s2 = s1 + 8192;                     // 8192
    __bf16* hFrag = (__bf16*)(s2 + 8192);      // 262144 float slots
    unsigned int* mask = (unsigned int*)(s2 + 8192 + 262144);  // 2097152 u32
    float* numP = s2 + 8192 + 262144 + 2097152;  // 1024*4096
    float* denP = numP + 1024 * 4096;            // 1024*64

    k_pack<<<2048, 256, 0, stream>>>(Adj, mask);
    k_gemm_h<<<256, 256, 0, stream>>>(X, W, h);
    k_s12<<<2048, 256, 0, stream>>>(h, a, s1, s2);
    k_hfrag<<<256, 256, 0, stream>>>(h, hFrag);
    k_attn4<<<1024, 256, 0, stream>>>((const bf16x8*)hFrag, mask, s1, s2, numP, denP);
    k_final<<<2048, 256, 0, stream>>>(numP, denP, out);
}